// Round 11
// baseline (415.068 us; speedup 1.0000x reference)
//
#include <hip/hip_runtime.h>
#include <hip/hip_bf16.h>
#include <cstdint>

#define VOCAB  50001
#define EMBED  64
#define HIDDEN 100
#define TSTEPS 512
#define BATCH  2048

typedef short bf16x8 __attribute__((ext_vector_type(8)));
typedef float f32x4  __attribute__((ext_vector_type(4)));

constexpr int RB = 32;               // batch rows per block: 2 groups of 16
constexpr int KP = 128;              // padded K for MFMA layout
constexpr int UP = 128;              // padded units (M)
constexpr int NBLK = BATCH / RB;     // 64 blocks

constexpr size_t WHH_BYTES = (size_t)UP * KP * 2;      // 32768 per half
constexpr size_t P_OFF     = 2 * WHH_BYTES;            // 65536
constexpr size_t P_BYTES   = (size_t)VOCAB * HIDDEN * 4;
constexpr size_t WS_NEED   = P_OFF + P_BYTES;

__device__ __forceinline__ float fast_tanh(float x) {
  const float e = __expf(2.0f * x);
  return 1.0f - 2.0f * __builtin_amdgcn_rcpf(e + 1.0f);
}
__device__ __forceinline__ unsigned cvt_pk_bf16(float a, float b) {
  unsigned r;
  asm("v_cvt_pk_bf16_f32 %0, %1, %2" : "=v"(r) : "v"(a), "v"(b));
  return r;
}
__device__ __forceinline__ f32x4 zf4() { f32x4 z = {0.f, 0.f, 0.f, 0.f}; return z; }

#define MFMA16(A,B,C) __builtin_amdgcn_mfma_f32_16x16x32_bf16((A),(B),(C),0,0,0)

// ---------------- P[v][j] = W_ih[j,:]·table[v,:] + b_ih[j] + b_hh[j] -----------
__global__ __launch_bounds__(128) void proj_kernel(
    const float* __restrict__ table, const float* __restrict__ Wih,
    const float* __restrict__ bih, const float* __restrict__ bhh,
    float* __restrict__ P)
{
  constexpr int VPB = 16;
  __shared__ float e[VPB][EMBED];
  const int vbase = blockIdx.x * VPB;
  const int tid = threadIdx.x;
  #pragma unroll
  for (int r = 0; r < VPB * EMBED / 128; ++r) {
    const int el = tid + 128 * r;
    const int v  = vbase + (el >> 6);
    e[el >> 6][el & 63] = (v < VOCAB) ? table[(size_t)v * EMBED + (el & 63)] : 0.f;
  }
  __syncthreads();

  const int j = (tid < HIDDEN) ? tid : HIDDEN - 1;
  float w[EMBED];
  #pragma unroll
  for (int k = 0; k < EMBED; k += 4) {
    const float4 t4 = *reinterpret_cast<const float4*>(&Wih[j * EMBED + k]);
    w[k] = t4.x; w[k+1] = t4.y; w[k+2] = t4.z; w[k+3] = t4.w;
  }
  const float bias = bih[j] + bhh[j];

  for (int r = 0; r < VPB; ++r) {
    const int v = vbase + r;
    if (v >= VOCAB) break;
    float acc = bias;
    #pragma unroll
    for (int k = 0; k < EMBED; k += 4) {
      const float4 ev = *reinterpret_cast<const float4*>(&e[r][k]);
      acc += w[k]*ev.x + w[k+1]*ev.y + w[k+2]*ev.z + w[k+3]*ev.w;
    }
    if (tid < HIDDEN) P[(size_t)v * HIDDEN + tid] = acc;
  }
}

// ---------------- Whh -> split-bf16 padded [UP][KP] (hi, lo) -------------------
__global__ __launch_bounds__(256) void prep_whh(
    const float* __restrict__ Whh, unsigned short* __restrict__ hi,
    unsigned short* __restrict__ lo)
{
  const int i = blockIdx.x * 256 + threadIdx.x;
  if (i >= UP * KP) return;
  const int u = i >> 7, k = i & (KP - 1);
  const float v = (u < HIDDEN && k < HIDDEN) ? Whh[u * HIDDEN + k] : 0.f;
  const unsigned b = __float_as_uint(v);
  const unsigned h16 = (b + 0x7FFFu + ((b >> 16) & 1u)) >> 16;
  const float hf = __uint_as_float(h16 << 16);
  const float r = v - hf;
  const unsigned rb = __float_as_uint(r);
  const unsigned l16 = (rb + 0x7FFFu + ((rb >> 16) & 1u)) >> 16;
  hi[i] = (unsigned short)h16;
  lo[i] = (unsigned short)l16;
}

// ---------------- MFMA recurrence: 32 rows/block = 2 independent groups --------
// Per phase (1 barrier): step t of group A AND group B. 4 interleaved MFMA
// chains (A-hi, B-hi, A-lo, B-lo) -> dependent latency hidden; B's compute
// fills A's LDS/VALU stalls. Math per group identical to the 192us R7 kernel.
__global__ __launch_bounds__(512, 1)
void rnn_mfma_kernel(const int* __restrict__ x, const unsigned char* __restrict__ ws,
                     const float* __restrict__ fcW, const float* __restrict__ fcb,
                     float* __restrict__ out)
{
  __shared__ __align__(16) unsigned char hbufA[2][4096]; // group A h, bf16
  __shared__ __align__(16) unsigned char hbufB[2][4096]; // group B h, bf16
  __shared__ unsigned short idx_lds[TSTEPS][RB];         // u16 ids (VOCAB<65536)
  __shared__ float red[2][64];

  const int tid = threadIdx.x;
  const int w   = tid >> 6;             // 0..7, tile index
  const int l   = tid & 63;
  const int row = l & 15;
  const int g   = l >> 4;
  const int row0 = blockIdx.x * RB;
  const unsigned swz = (unsigned)((row & 7) << 4);

  // zero h buffers (h0 = 0): 2 x 8192 B = 1024 uint4
  reinterpret_cast<uint4*>(&hbufA[0][0])[tid] = make_uint4(0u, 0u, 0u, 0u);
  reinterpret_cast<uint4*>(&hbufB[0][0])[tid] = make_uint4(0u, 0u, 0u, 0u);

  // stage x indices transposed as u16: idx_lds[t][r]
  {
    const int r = tid >> 4, tl = tid & 15;
    const int* __restrict__ xr = x + (size_t)(row0 + r) * TSTEPS;
    #pragma unroll
    for (int c = 0; c < TSTEPS / 16; ++c) {
      const int t = tl + 16 * c;
      idx_lds[t][r] = (unsigned short)xr[t];
    }
  }

  const unsigned char* __restrict__ WH = ws;
  const unsigned char* __restrict__ WL = ws + WHH_BYTES;
  const float* __restrict__ Pb = reinterpret_cast<const float*>(ws + P_OFF);

  // loop-invariant A fragments (W split hi/lo), tile mt = w — shared by groups
  bf16x8 whi[4], wlo[4];
  #pragma unroll
  for (int kt = 0; kt < 4; ++kt) {
    const unsigned off = (unsigned)(w * 16 + row) * 256u + (unsigned)(kt * 64 + g * 16);
    whi[kt] = *reinterpret_cast<const bf16x8*>(WH + off);
    wlo[kt] = *reinterpret_cast<const bf16x8*>(WL + off);
  }

  const int useed  = w * 16 + g * 4;                // unit base for D frag
  const int useedc = (useed <= 96) ? useed : 96;    // clamp P col for pad units

  __syncthreads();

  // seed regs: even/odd parity per group, depth-2 prefetch
  f32x4 SAe, SAo, SBe, SBo;
  {
    const int a0 = idx_lds[0][row],      a1 = idx_lds[1][row];
    const int b0 = idx_lds[0][16 + row], b1 = idx_lds[1][16 + row];
    SAe = *reinterpret_cast<const f32x4*>(Pb + (size_t)a0 * HIDDEN + useedc);
    SAo = *reinterpret_cast<const f32x4*>(Pb + (size_t)a1 * HIDDEN + useedc);
    SBe = *reinterpret_cast<const f32x4*>(Pb + (size_t)b0 * HIDDEN + useedc);
    SBo = *reinterpret_cast<const f32x4*>(Pb + (size_t)b1 * HIDDEN + useedc);
  }

  auto fused = [&](int t, const unsigned char* rA, unsigned char* wA,
                   const unsigned char* rB, unsigned char* wB,
                   f32x4 &Sa, f32x4 &Sb) {
    // issue all 8 ds_reads upfront (A then B), XOR-swizzled rows
    bf16x8 bA[4], bB[4];
    #pragma unroll
    for (int kt = 0; kt < 4; ++kt) {
      const unsigned off = ((unsigned)(row * 256 + kt * 64 + g * 16)) ^ swz;
      bA[kt] = *reinterpret_cast<const bf16x8*>(rA + off);
      bB[kt] = *reinterpret_cast<const bf16x8*>(rB + off);
    }
    // 4 interleaved independent MFMA chains
    f32x4 a1 = Sa, a3 = zf4(), b1 = Sb, b3 = zf4();
    #pragma unroll
    for (int kt = 0; kt < 4; ++kt) {
      a1 = MFMA16(whi[kt], bA[kt], a1);
      b1 = MFMA16(whi[kt], bB[kt], b1);
      a3 = MFMA16(wlo[kt], bA[kt], a3);
      b3 = MFMA16(wlo[kt], bB[kt], b3);
    }
    const f32x4 dA = a1 + a3;
    const f32x4 dB = b1 + b3;
    // refill seeds for t+2 (hides gather latency across a full phase)
    {
      const int tn = (t + 2 < TSTEPS) ? t + 2 : TSTEPS - 1;
      const int xa = idx_lds[tn][row];
      const int xb = idx_lds[tn][16 + row];
      Sa = *reinterpret_cast<const f32x4*>(Pb + (size_t)xa * HIDDEN + useedc);
      Sb = *reinterpret_cast<const f32x4*>(Pb + (size_t)xb * HIDDEN + useedc);
    }
    // tanh -> bf16 -> LDS, both groups
    {
      const unsigned pa01 = cvt_pk_bf16(fast_tanh(dA[0]), fast_tanh(dA[1]));
      const unsigned pa23 = cvt_pk_bf16(fast_tanh(dA[2]), fast_tanh(dA[3]));
      const unsigned pb01 = cvt_pk_bf16(fast_tanh(dB[0]), fast_tanh(dB[1]));
      const unsigned pb23 = cvt_pk_bf16(fast_tanh(dB[2]), fast_tanh(dB[3]));
      const unsigned off = ((unsigned)(row * 256 + useed * 2)) ^ swz;
      *reinterpret_cast<uint2*>(wA + off) = make_uint2(pa01, pa23);
      *reinterpret_cast<uint2*>(wB + off) = make_uint2(pb01, pb23);
    }
    __syncthreads();
  };

  for (int t = 0; t < TSTEPS; t += 2) {
    fused(t,     &hbufA[0][0], &hbufA[1][0], &hbufB[0][0], &hbufB[1][0], SAe, SBe);
    fused(t + 1, &hbufA[1][0], &hbufA[0][0], &hbufB[1][0], &hbufB[0][0], SAo, SBo);
  }

  // FC + sigmoid (final h in hbufA[0] / hbufB[0]); wave 0 -> A, wave 1 -> B
  if (w < 2) {
    const unsigned char* hbF = (w == 0) ? &hbufA[0][0] : &hbufB[0][0];
    float part = 0.f;
    for (int i = 0; i < 25; ++i) {
      const int u = g * 25 + i;
      const unsigned off = ((unsigned)(row * 256 + u * 2)) ^ swz;
      const unsigned short vh = *reinterpret_cast<const unsigned short*>(hbF + off);
      const float hv = __uint_as_float((unsigned)vh << 16);
      part += hv * fcW[u];
    }
    red[w][l] = part;
  }
  __syncthreads();
  if (tid < RB) {
    const int grp = tid >> 4, r = tid & 15;
    const float s = red[grp][r] + red[grp][r + 16] + red[grp][r + 32] +
                    red[grp][r + 48] + fcb[0];
    out[row0 + grp * 16 + r] = 1.0f / (1.0f + __expf(-s));
  }
}

// ---------------- fallback: exact fp32 wave kernel -----------------------------
__global__ __launch_bounds__(64)
__attribute__((amdgpu_waves_per_eu(2, 2)))
void rnn_wave_kernel(
    const int* __restrict__ x, const float* __restrict__ P,
    const float* __restrict__ Whh,
    const float* __restrict__ fcW, const float* __restrict__ fcb,
    float* __restrict__ out)
{
  __shared__ float h_lds[2][112];
  const int row = blockIdx.x;
  const int l = threadIdx.x;
  const int u0 = l;
  const bool m1 = (l < HIDDEN - 64);
  const int u1 = m1 ? (64 + l) : (HIDDEN - 1);

  float w0[HIDDEN], w1[HIDDEN];
  #pragma unroll
  for (int k = 0; k < HIDDEN; k += 4) {
    const float4 a = *reinterpret_cast<const float4*>(&Whh[u0 * HIDDEN + k]);
    w0[k] = a.x; w0[k+1] = a.y; w0[k+2] = a.z; w0[k+3] = a.w;
    const float4 b = *reinterpret_cast<const float4*>(&Whh[u1 * HIDDEN + k]);
    w1[k] = b.x; w1[k+1] = b.y; w1[k+2] = b.z; w1[k+3] = b.w;
  }
  const float fw0 = fcW[u0];
  const float fw1 = m1 ? fcW[u1] : 0.f;

  h_lds[0][l] = 0.f;
  h_lds[0][l + 48] = 0.f;

  const int* __restrict__ xrow = x + (size_t)row * TSTEPS;
  const int i0 = xrow[0];
  float xp0 = P[i0 * HIDDEN + u0];
  float xp1 = P[i0 * HIDDEN + u1];
  int i_nx = xrow[1];

  float h0 = 0.f, h1 = 0.f;
  for (int t = 0; t < TSTEPS; ++t) {
    const int cur = t & 1, nxt = cur ^ 1;
    const float* __restrict__ Prow = P + i_nx * HIDDEN;
    const float xp0n = Prow[u0];
    const float xp1n = Prow[u1];
    i_nx = (t + 2 < TSTEPS) ? xrow[t + 2] : 0;

    float a0 = xp0, b0 = 0.f, a1v = xp1, b1 = 0.f;
    const float4* __restrict__ hb = reinterpret_cast<const float4*>(&h_lds[cur][0]);
    #pragma unroll
    for (int gq = 0; gq < HIDDEN / 4; ++gq) {
      const float4 hv = hb[gq];
      const int k = 4 * gq;
      if ((gq & 1) == 0) {
        a0  += w0[k]*hv.x + w0[k+1]*hv.y + w0[k+2]*hv.z + w0[k+3]*hv.w;
        a1v += w1[k]*hv.x + w1[k+1]*hv.y + w1[k+2]*hv.z + w1[k+3]*hv.w;
      } else {
        b0 += w0[k]*hv.x + w0[k+1]*hv.y + w0[k+2]*hv.z + w0[k+3]*hv.w;
        b1 += w1[k]*hv.x + w1[k+1]*hv.y + w1[k+2]*hv.z + w1[k+3]*hv.w;
      }
    }
    h0 = fast_tanh(a0 + b0);
    h1 = fast_tanh(a1v + b1);
    h_lds[nxt][u0] = h0;
    if (m1) h_lds[nxt][u1] = h1;
    xp0 = xp0n; xp1 = xp1n;
  }

  float s = h0 * fw0 + (m1 ? h1 * fw1 : 0.f);
  #pragma unroll
  for (int off = 32; off > 0; off >>= 1) s += __shfl_down(s, off);
  if (l == 0) out[row] = 1.0f / (1.0f + __expf(-(s + fcb[0])));
}

// ---------------- host ----------------------------------------------------------
extern "C" void kernel_launch(void* const* d_in, const int* in_sizes, int n_in,
                              void* d_out, int out_size, void* d_ws, size_t ws_size,
                              hipStream_t stream) {
  const int*   x     = (const int*)  d_in[0];
  const float* table = (const float*)d_in[1];
  const float* Wih   = (const float*)d_in[2];
  const float* Whh   = (const float*)d_in[3];
  const float* bih   = (const float*)d_in[4];
  const float* bhh   = (const float*)d_in[5];
  const float* fcW   = (const float*)d_in[6];
  const float* fcb   = (const float*)d_in[7];
  float* out = (float*)d_out;

  unsigned char* ws = (unsigned char*)d_ws;

  if (ws_size >= WS_NEED) {
    unsigned short* WhhHi = (unsigned short*)ws;
    unsigned short* WhhLo = (unsigned short*)(ws + WHH_BYTES);
    float* Pt = (float*)(ws + P_OFF);
    prep_whh<<<(UP * KP + 255) / 256, 256, 0, stream>>>(Whh, WhhHi, WhhLo);
    proj_kernel<<<(VOCAB + 15) / 16, 128, 0, stream>>>(table, Wih, bih, bhh, Pt);
    rnn_mfma_kernel<<<NBLK, 512, 0, stream>>>(x, ws, fcW, fcb, out);
  } else {
    float* Pt = (float*)ws;
    proj_kernel<<<(VOCAB + 15) / 16, 128, 0, stream>>>(table, Wih, bih, bhh, Pt);
    rnn_wave_kernel<<<BATCH, 64, 0, stream>>>(x, Pt, Whh, fcW, fcb, out);
  }
}

// Round 12
// 302.131 us; speedup vs baseline: 1.3738x; 1.3738x over previous
//
#include <hip/hip_runtime.h>
#include <hip/hip_bf16.h>
#include <cstdint>

#define VOCAB  50001
#define EMBED  64
#define HIDDEN 100
#define TSTEPS 512
#define BATCH  2048

typedef short bf16x8 __attribute__((ext_vector_type(8)));
typedef float f32x4  __attribute__((ext_vector_type(4)));

constexpr int RB = 16;               // batch rows per block
constexpr int KP = 128;              // padded K (hidden) for MFMA layout
constexpr int UP = 128;              // padded units (M)
constexpr int NBLK = BATCH / RB;     // 128 blocks

constexpr size_t WHH_BYTES = (size_t)UP * KP * 2;      // 32768 per half
constexpr size_t P_OFF     = 2 * WHH_BYTES;            // 65536
constexpr size_t P_BYTES   = (size_t)VOCAB * HIDDEN * 4;
constexpr size_t WS_NEED   = P_OFF + P_BYTES;

__device__ __forceinline__ float fast_tanh(float x) {
  const float e = __expf(2.0f * x);
  return 1.0f - 2.0f * __builtin_amdgcn_rcpf(e + 1.0f);
}
__device__ __forceinline__ unsigned cvt_pk_bf16(float a, float b) {
  unsigned r;
  asm("v_cvt_pk_bf16_f32 %0, %1, %2" : "=v"(r) : "v"(a), "v"(b));
  return r;
}
__device__ __forceinline__ f32x4 zf4() { f32x4 z = {0.f, 0.f, 0.f, 0.f}; return z; }

#define MFMA16(A,B,C) __builtin_amdgcn_mfma_f32_16x16x32_bf16((A),(B),(C),0,0,0)

// ---------------- P[v][j] = W_ih[j,:]·table[v,:] + b_ih[j] + b_hh[j] -----------
__global__ __launch_bounds__(128) void proj_kernel(
    const float* __restrict__ table, const float* __restrict__ Wih,
    const float* __restrict__ bih, const float* __restrict__ bhh,
    float* __restrict__ P)
{
  constexpr int VPB = 16;
  __shared__ float e[VPB][EMBED];
  const int vbase = blockIdx.x * VPB;
  const int tid = threadIdx.x;
  #pragma unroll
  for (int r = 0; r < VPB * EMBED / 128; ++r) {
    const int el = tid + 128 * r;
    const int v  = vbase + (el >> 6);
    e[el >> 6][el & 63] = (v < VOCAB) ? table[(size_t)v * EMBED + (el & 63)] : 0.f;
  }
  __syncthreads();

  const int j = (tid < HIDDEN) ? tid : HIDDEN - 1;
  float w[EMBED];
  #pragma unroll
  for (int k = 0; k < EMBED; k += 4) {
    const float4 t4 = *reinterpret_cast<const float4*>(&Wih[j * EMBED + k]);
    w[k] = t4.x; w[k+1] = t4.y; w[k+2] = t4.z; w[k+3] = t4.w;
  }
  const float bias = bih[j] + bhh[j];

  for (int r = 0; r < VPB; ++r) {
    const int v = vbase + r;
    if (v >= VOCAB) break;
    float acc = bias;
    #pragma unroll
    for (int k = 0; k < EMBED; k += 4) {
      const float4 ev = *reinterpret_cast<const float4*>(&e[r][k]);
      acc += w[k]*ev.x + w[k+1]*ev.y + w[k+2]*ev.z + w[k+3]*ev.w;
    }
    if (tid < HIDDEN) P[(size_t)v * HIDDEN + tid] = acc;
  }
}

// ---------------- Whh -> split-bf16 padded [UP][KP] (hi, lo) -------------------
__global__ __launch_bounds__(256) void prep_whh(
    const float* __restrict__ Whh, unsigned short* __restrict__ hi,
    unsigned short* __restrict__ lo)
{
  const int i = blockIdx.x * 256 + threadIdx.x;
  if (i >= UP * KP) return;
  const int u = i >> 7, k = i & (KP - 1);
  const float v = (u < HIDDEN && k < HIDDEN) ? Whh[u * HIDDEN + k] : 0.f;
  const unsigned b = __float_as_uint(v);
  const unsigned h16 = (b + 0x7FFFu + ((b >> 16) & 1u)) >> 16;
  const float hf = __uint_as_float(h16 << 16);
  const float r = v - hf;
  const unsigned rb = __float_as_uint(r);
  const unsigned l16 = (rb + 0x7FFFu + ((rb >> 16) & 1u)) >> 16;
  hi[i] = (unsigned short)h16;
  lo[i] = (unsigned short)l16;
}

// ---------------- MFMA recurrence: 16 rows/block, 8 waves, 1 tile/wave ---------
// R7 structure exactly (192us measured best); ONLY change: the 8 MFMAs are
// arranged as 4 independent chains of depth 2 (was 2 chains of depth 4) to
// halve exposed MFMA dependency latency. Same instruction count, same layout,
// same sync.
__global__ __launch_bounds__(512, 1)
void rnn_mfma_kernel(const int* __restrict__ x, const unsigned char* __restrict__ ws,
                     const float* __restrict__ fcW, const float* __restrict__ fcb,
                     float* __restrict__ out)
{
  __shared__ __align__(16) unsigned char hbuf[2][4096]; // [buf][16 rows][128 k] bf16
  __shared__ int idx_lds[TSTEPS][RB];
  __shared__ float red[64];

  const int tid = threadIdx.x;
  const int w   = tid >> 6;             // 0..7, tile index
  const int l   = tid & 63;
  const int row = l & 15;
  const int g   = l >> 4;
  const int row0 = blockIdx.x * RB;
  const unsigned swz = (unsigned)((row & 7) << 4);

  // zero h buffers (doubles as h0 = 0): 512 uint4 = 8192 B
  reinterpret_cast<uint4*>(&hbuf[0][0])[tid] = make_uint4(0u, 0u, 0u, 0u);

  // stage x indices transposed: idx_lds[t][r]; coalesced per row
  {
    const int r = tid >> 5, tl = tid & 31;
    const int* __restrict__ xr = x + (size_t)(row0 + r) * TSTEPS;
    #pragma unroll
    for (int c = 0; c < TSTEPS / 32; ++c) {
      const int t = tl + 32 * c;
      idx_lds[t][r] = xr[t];
    }
  }

  const unsigned char* __restrict__ WH = ws;
  const unsigned char* __restrict__ WL = ws + WHH_BYTES;
  const float* __restrict__ Pb = reinterpret_cast<const float*>(ws + P_OFF);

  // loop-invariant A fragments in registers (W split hi/lo), tile mt = w
  bf16x8 whi[4], wlo[4];
  #pragma unroll
  for (int kt = 0; kt < 4; ++kt) {
    const unsigned off = (unsigned)(w * 16 + row) * 256u + (unsigned)(kt * 64 + g * 16);
    whi[kt] = *reinterpret_cast<const bf16x8*>(WH + off);
    wlo[kt] = *reinterpret_cast<const bf16x8*>(WL + off);
  }

  const int useed  = w * 16 + g * 4;                // unit base for D frag
  const int useedc = (useed <= 96) ? useed : 96;    // clamp P col for pad units

  __syncthreads();

  // seed prefetch (depth 2): SA for even steps, SB for odd
  f32x4 SA, SB;
  {
    const int x0 = idx_lds[0][row];
    const int x1 = idx_lds[1][row];
    SA = *reinterpret_cast<const f32x4*>(Pb + (size_t)x0 * HIDDEN + useedc);
    SB = *reinterpret_cast<const f32x4*>(Pb + (size_t)x1 * HIDDEN + useedc);
  }

  auto body = [&](int t, const unsigned char* hbR, unsigned char* hbW, f32x4 &S) {
    // B fragments (h bf16), XOR-swizzled rows
    bf16x8 bhi[4];
    #pragma unroll
    for (int kt = 0; kt < 4; ++kt) {
      const unsigned off = ((unsigned)(row * 256 + kt * 64 + g * 16)) ^ swz;
      bhi[kt] = *reinterpret_cast<const bf16x8*>(hbR + off);
    }
    // 4 independent MFMA chains of depth 2 (same 8 MFMAs as before)
    f32x4 c0 = MFMA16(whi[0], bhi[0], S);
    f32x4 c1 = MFMA16(whi[1], bhi[1], zf4());
    f32x4 c2 = MFMA16(wlo[0], bhi[0], zf4());
    f32x4 c3 = MFMA16(wlo[1], bhi[1], zf4());
    c0 = MFMA16(whi[2], bhi[2], c0);
    c1 = MFMA16(whi[3], bhi[3], c1);
    c2 = MFMA16(wlo[2], bhi[2], c2);
    c3 = MFMA16(wlo[3], bhi[3], c3);
    const f32x4 d0 = (c0 + c1) + (c2 + c3);
    // refill seed for t+2 (prefetch hides L2/L3/HBM gather latency)
    {
      const int tn = (t + 2 < TSTEPS) ? t + 2 : TSTEPS - 1;
      const int xt = idx_lds[tn][row];
      S = *reinterpret_cast<const f32x4*>(Pb + (size_t)xt * HIDDEN + useedc);
    }
    // tanh -> bf16 -> LDS
    {
      const unsigned ph01 = cvt_pk_bf16(fast_tanh(d0[0]), fast_tanh(d0[1]));
      const unsigned ph23 = cvt_pk_bf16(fast_tanh(d0[2]), fast_tanh(d0[3]));
      const unsigned off = ((unsigned)(row * 256 + useed * 2)) ^ swz;
      *reinterpret_cast<uint2*>(hbW + off) = make_uint2(ph01, ph23);
    }
    __syncthreads();
  };

  for (int t = 0; t < TSTEPS; t += 2) {
    body(t,     &hbuf[0][0], &hbuf[1][0], SA);
    body(t + 1, &hbuf[1][0], &hbuf[0][0], SB);
  }

  // FC + sigmoid (final h is in hbuf[0])
  if (w == 0) {
    const unsigned char* hbF = &hbuf[0][0];
    float part = 0.f;
    for (int i = 0; i < 25; ++i) {
      const int u = g * 25 + i;
      const unsigned off = ((unsigned)(row * 256 + u * 2)) ^ swz;
      const unsigned short vh = *reinterpret_cast<const unsigned short*>(hbF + off);
      const float hv = __uint_as_float((unsigned)vh << 16);
      part += hv * fcW[u];
    }
    red[l] = part;
  }
  __syncthreads();
  if (tid < RB) {
    const float s = red[tid] + red[tid + 16] + red[tid + 32] + red[tid + 48] + fcb[0];
    out[row0 + tid] = 1.0f / (1.0f + __expf(-s));
  }
}

// ---------------- fallback: exact fp32 wave kernel -----------------------------
__global__ __launch_bounds__(64)
__attribute__((amdgpu_waves_per_eu(2, 2)))
void rnn_wave_kernel(
    const int* __restrict__ x, const float* __restrict__ P,
    const float* __restrict__ Whh,
    const float* __restrict__ fcW, const float* __restrict__ fcb,
    float* __restrict__ out)
{
  __shared__ float h_lds[2][112];
  const int row = blockIdx.x;
  const int l = threadIdx.x;
  const int u0 = l;
  const bool m1 = (l < HIDDEN - 64);
  const int u1 = m1 ? (64 + l) : (HIDDEN - 1);

  float w0[HIDDEN], w1[HIDDEN];
  #pragma unroll
  for (int k = 0; k < HIDDEN; k += 4) {
    const float4 a = *reinterpret_cast<const float4*>(&Whh[u0 * HIDDEN + k]);
    w0[k] = a.x; w0[k+1] = a.y; w0[k+2] = a.z; w0[k+3] = a.w;
    const float4 b = *reinterpret_cast<const float4*>(&Whh[u1 * HIDDEN + k]);
    w1[k] = b.x; w1[k+1] = b.y; w1[k+2] = b.z; w1[k+3] = b.w;
  }
  const float fw0 = fcW[u0];
  const float fw1 = m1 ? fcW[u1] : 0.f;

  h_lds[0][l] = 0.f;
  h_lds[0][l + 48] = 0.f;

  const int* __restrict__ xrow = x + (size_t)row * TSTEPS;
  const int i0 = xrow[0];
  float xp0 = P[i0 * HIDDEN + u0];
  float xp1 = P[i0 * HIDDEN + u1];
  int i_nx = xrow[1];

  float h0 = 0.f, h1 = 0.f;
  for (int t = 0; t < TSTEPS; ++t) {
    const int cur = t & 1, nxt = cur ^ 1;
    const float* __restrict__ Prow = P + i_nx * HIDDEN;
    const float xp0n = Prow[u0];
    const float xp1n = Prow[u1];
    i_nx = (t + 2 < TSTEPS) ? xrow[t + 2] : 0;

    float a0 = xp0, b0 = 0.f, a1v = xp1, b1 = 0.f;
    const float4* __restrict__ hb = reinterpret_cast<const float4*>(&h_lds[cur][0]);
    #pragma unroll
    for (int gq = 0; gq < HIDDEN / 4; ++gq) {
      const float4 hv = hb[gq];
      const int k = 4 * gq;
      if ((gq & 1) == 0) {
        a0  += w0[k]*hv.x + w0[k+1]*hv.y + w0[k+2]*hv.z + w0[k+3]*hv.w;
        a1v += w1[k]*hv.x + w1[k+1]*hv.y + w1[k+2]*hv.z + w1[k+3]*hv.w;
      } else {
        b0 += w0[k]*hv.x + w0[k+1]*hv.y + w0[k+2]*hv.z + w0[k+3]*hv.w;
        b1 += w1[k]*hv.x + w1[k+1]*hv.y + w1[k+2]*hv.z + w1[k+3]*hv.w;
      }
    }
    h0 = fast_tanh(a0 + b0);
    h1 = fast_tanh(a1v + b1);
    h_lds[nxt][u0] = h0;
    if (m1) h_lds[nxt][u1] = h1;
    xp0 = xp0n; xp1 = xp1n;
  }

  float s = h0 * fw0 + (m1 ? h1 * fw1 : 0.f);
  #pragma unroll
  for (int off = 32; off > 0; off >>= 1) s += __shfl_down(s, off);
  if (l == 0) out[row] = 1.0f / (1.0f + __expf(-(s + fcb[0])));
}

// ---------------- host ----------------------------------------------------------
extern "C" void kernel_launch(void* const* d_in, const int* in_sizes, int n_in,
                              void* d_out, int out_size, void* d_ws, size_t ws_size,
                              hipStream_t stream) {
  const int*   x     = (const int*)  d_in[0];
  const float* table = (const float*)d_in[1];
  const float* Wih   = (const float*)d_in[2];
  const float* Whh   = (const float*)d_in[3];
  const float* bih   = (const float*)d_in[4];
  const float* bhh   = (const float*)d_in[5];
  const float* fcW   = (const float*)d_in[6];
  const float* fcb   = (const float*)d_in[7];
  float* out = (float*)d_out;

  unsigned char* ws = (unsigned char*)d_ws;

  if (ws_size >= WS_NEED) {
    unsigned short* WhhHi = (unsigned short*)ws;
    unsigned short* WhhLo = (unsigned short*)(ws + WHH_BYTES);
    float* Pt = (float*)(ws + P_OFF);
    prep_whh<<<(UP * KP + 255) / 256, 256, 0, stream>>>(Whh, WhhHi, WhhLo);
    proj_kernel<<<(VOCAB + 15) / 16, 128, 0, stream>>>(table, Wih, bih, bhh, Pt);
    rnn_mfma_kernel<<<NBLK, 512, 0, stream>>>(x, ws, fcW, fcb, out);
  } else {
    float* Pt = (float*)ws;
    proj_kernel<<<(VOCAB + 15) / 16, 128, 0, stream>>>(table, Wih, bih, bhh, Pt);
    rnn_wave_kernel<<<BATCH, 64, 0, stream>>>(x, Pt, Whh, fcW, fcb, out);
  }
}

// Round 13
// 283.993 us; speedup vs baseline: 1.4615x; 1.0639x over previous
//
#include <hip/hip_runtime.h>
#include <hip/hip_bf16.h>
#include <cstdint>

#define VOCAB  50001
#define EMBED  64
#define HIDDEN 100
#define TSTEPS 512
#define BATCH  2048

typedef short bf16x8 __attribute__((ext_vector_type(8)));
typedef float f32x4  __attribute__((ext_vector_type(4)));

constexpr int RB = 16;               // batch rows per block
constexpr int NBLK = BATCH / RB;     // 128 blocks

constexpr size_t P_BYTES = (size_t)VOCAB * HIDDEN * 4;
constexpr size_t WS_NEED = P_BYTES;  // ws = P table only (W converted inline)

__device__ __forceinline__ float fast_tanh(float x) {
  const float e = __expf(2.0f * x);
  return 1.0f - 2.0f * __builtin_amdgcn_rcpf(e + 1.0f);
}
__device__ __forceinline__ unsigned cvt_pk_bf16(float a, float b) {
  unsigned r;
  asm("v_cvt_pk_bf16_f32 %0, %1, %2" : "=v"(r) : "v"(a), "v"(b));
  return r;
}
__device__ __forceinline__ f32x4 zf4() { f32x4 z = {0.f, 0.f, 0.f, 0.f}; return z; }

#define MFMA16(A,B,C) __builtin_amdgcn_mfma_f32_16x16x32_bf16((A),(B),(C),0,0,0)

// split 8 fp32 -> bf16-hi + bf16-lo fragments (RNE; residual exact in f32)
__device__ __forceinline__ void cvt8_split(const float* f, bf16x8 &hi, bf16x8 &lo) {
  union { unsigned u[4]; bf16x8 v; } H, L;
  #pragma unroll
  for (int p = 0; p < 4; ++p) {
    const unsigned h = cvt_pk_bf16(f[2*p], f[2*p+1]);
    const float r0 = f[2*p]   - __uint_as_float(h << 16);
    const float r1 = f[2*p+1] - __uint_as_float(h & 0xFFFF0000u);
    H.u[p] = h;
    L.u[p] = cvt_pk_bf16(r0, r1);
  }
  hi = H.v; lo = L.v;
}

// ---------------- P[v][j] = W_ih[j,:]·table[v,:] + b_ih[j] + b_hh[j] -----------
// 256 threads: 2 groups x 128; group q computes rows q*16..q*16+15 of a
// 32-row vocab tile. Rows processed in pairs for FMA ILP.
__global__ __launch_bounds__(256) void proj_kernel(
    const float* __restrict__ table, const float* __restrict__ Wih,
    const float* __restrict__ bih, const float* __restrict__ bhh,
    float* __restrict__ P)
{
  constexpr int VPB = 32;
  __shared__ float e[VPB][EMBED];
  const int vbase = blockIdx.x * VPB;
  const int tid = threadIdx.x;
  // stage 32 consecutive embedding rows, fully coalesced (8 iters x 256)
  #pragma unroll
  for (int i = 0; i < VPB * EMBED / 256; ++i) {
    const int el = tid + 256 * i;
    const int v  = vbase + (el >> 6);
    e[el >> 6][el & 63] = (v < VOCAB) ? table[(size_t)v * EMBED + (el & 63)] : 0.f;
  }
  __syncthreads();

  const int q  = tid >> 7;              // row-group 0/1
  const int jt = tid & 127;
  const int j  = (jt < HIDDEN) ? jt : HIDDEN - 1;
  float w[EMBED];
  #pragma unroll
  for (int k = 0; k < EMBED; k += 4) {
    const float4 t4 = *reinterpret_cast<const float4*>(&Wih[j * EMBED + k]);
    w[k] = t4.x; w[k+1] = t4.y; w[k+2] = t4.z; w[k+3] = t4.w;
  }
  const float bias = bih[j] + bhh[j];

  #pragma unroll
  for (int r2 = 0; r2 < 16; r2 += 2) {
    const int r0 = q * 16 + r2, r1 = r0 + 1;
    const int v0 = vbase + r0, v1 = vbase + r1;
    float acc0 = bias, acc1 = bias;
    #pragma unroll
    for (int k = 0; k < EMBED; k += 4) {
      const float4 e0 = *reinterpret_cast<const float4*>(&e[r0][k]);
      const float4 e1 = *reinterpret_cast<const float4*>(&e[r1][k]);
      acc0 += w[k]*e0.x + w[k+1]*e0.y + w[k+2]*e0.z + w[k+3]*e0.w;
      acc1 += w[k]*e1.x + w[k+1]*e1.y + w[k+2]*e1.z + w[k+3]*e1.w;
    }
    if (jt < HIDDEN && v0 < VOCAB) P[(size_t)v0 * HIDDEN + jt] = acc0;
    if (jt < HIDDEN && v1 < VOCAB) P[(size_t)v1 * HIDDEN + jt] = acc1;
  }
}

// ---------------- MFMA recurrence: 16 rows/block, 8 waves, 1 tile/wave ---------
// R7 structure EXACTLY (the 192us measured optimum): 8 MFMAs/wave as 2 split
// chains of depth 4, plain __syncthreads, all 8 waves compute (wave 7 = pad).
// Only change vs R7: W fragments converted inline from fp32 Whh (prep_whh
// kernel eliminated).
__global__ __launch_bounds__(512, 1)
void rnn_mfma_kernel(const int* __restrict__ x, const float* __restrict__ Pb,
                     const float* __restrict__ Whh,
                     const float* __restrict__ fcW, const float* __restrict__ fcb,
                     float* __restrict__ out)
{
  __shared__ __align__(16) unsigned char hbuf[2][4096]; // [buf][16 rows][128 k] bf16
  __shared__ int idx_lds[TSTEPS][RB];
  __shared__ float red[64];

  const int tid = threadIdx.x;
  const int w   = tid >> 6;             // 0..7, tile index
  const int l   = tid & 63;
  const int row = l & 15;
  const int g   = l >> 4;
  const int row0 = blockIdx.x * RB;
  const unsigned swz = (unsigned)((row & 7) << 4);

  // zero h buffers (doubles as h0 = 0): 512 uint4 = 8192 B
  reinterpret_cast<uint4*>(&hbuf[0][0])[tid] = make_uint4(0u, 0u, 0u, 0u);

  // stage x indices transposed: idx_lds[t][r]; coalesced per row
  {
    const int r = tid >> 5, tl = tid & 31;
    const int* __restrict__ xr = x + (size_t)(row0 + r) * TSTEPS;
    #pragma unroll
    for (int c = 0; c < TSTEPS / 32; ++c) {
      const int t = tl + 32 * c;
      idx_lds[t][r] = xr[t];
    }
  }

  // loop-invariant A fragments: convert fp32 Whh -> split bf16 inline.
  // lane needs k = kt*32 + g*8 .. +7 of unit u = w*16+row (zeros outside).
  bf16x8 whi[4], wlo[4];
  {
    const int u = w * 16 + row;
    float f[8];
    #pragma unroll
    for (int kt = 0; kt < 4; ++kt) {
      const int k0 = kt * 32 + g * 8;
      if (u < HIDDEN && k0 + 7 < HIDDEN) {          // kt<3 always; safe
        const float4 a = *reinterpret_cast<const float4*>(&Whh[u * HIDDEN + k0]);
        const float4 b = *reinterpret_cast<const float4*>(&Whh[u * HIDDEN + k0 + 4]);
        f[0]=a.x; f[1]=a.y; f[2]=a.z; f[3]=a.w;
        f[4]=b.x; f[5]=b.y; f[6]=b.z; f[7]=b.w;
      } else if (u < HIDDEN && k0 < HIDDEN) {       // kt=3, g=0: k 96..99
        const float4 a = *reinterpret_cast<const float4*>(&Whh[u * HIDDEN + k0]);
        f[0]=a.x; f[1]=a.y; f[2]=a.z; f[3]=a.w;
        f[4]=0.f; f[5]=0.f; f[6]=0.f; f[7]=0.f;
      } else {
        #pragma unroll
        for (int p = 0; p < 8; ++p) f[p] = 0.f;
      }
      cvt8_split(f, whi[kt], wlo[kt]);
    }
  }

  const int useed  = w * 16 + g * 4;                // unit base for D frag
  const int useedc = (useed <= 96) ? useed : 96;    // clamp P col for pad units

  __syncthreads();

  // seed prefetch (depth 2): SA for even steps, SB for odd
  f32x4 SA, SB;
  {
    const int x0 = idx_lds[0][row];
    const int x1 = idx_lds[1][row];
    SA = *reinterpret_cast<const f32x4*>(Pb + (size_t)x0 * HIDDEN + useedc);
    SB = *reinterpret_cast<const f32x4*>(Pb + (size_t)x1 * HIDDEN + useedc);
  }

  auto body = [&](int t, const unsigned char* hbR, unsigned char* hbW, f32x4 &S) {
    // B fragments (h bf16), XOR-swizzled rows -> ~2-way conflicts
    bf16x8 bhi[4];
    #pragma unroll
    for (int kt = 0; kt < 4; ++kt) {
      const unsigned off = ((unsigned)(row * 256 + kt * 64 + g * 16)) ^ swz;
      bhi[kt] = *reinterpret_cast<const bf16x8*>(hbR + off);
    }
    // 2 split products on independent accumulators: 8 MFMAs (R7-exact)
    f32x4 a1 = S, a3 = zf4();
    #pragma unroll
    for (int kt = 0; kt < 4; ++kt) {
      a1 = MFMA16(whi[kt], bhi[kt], a1);
      a3 = MFMA16(wlo[kt], bhi[kt], a3);
    }
    const f32x4 d0 = a1 + a3;
    // refill seed for t+2 (prefetch hides L2/L3 gather latency)
    {
      const int tn = (t + 2 < TSTEPS) ? t + 2 : TSTEPS - 1;
      const int xt = idx_lds[tn][row];
      S = *reinterpret_cast<const f32x4*>(Pb + (size_t)xt * HIDDEN + useedc);
    }
    // tanh -> bf16 -> LDS
    {
      const unsigned ph01 = cvt_pk_bf16(fast_tanh(d0[0]), fast_tanh(d0[1]));
      const unsigned ph23 = cvt_pk_bf16(fast_tanh(d0[2]), fast_tanh(d0[3]));
      const unsigned off = ((unsigned)(row * 256 + useed * 2)) ^ swz;
      *reinterpret_cast<uint2*>(hbW + off) = make_uint2(ph01, ph23);
    }
    __syncthreads();
  };

  for (int t = 0; t < TSTEPS; t += 2) {
    body(t,     &hbuf[0][0], &hbuf[1][0], SA);
    body(t + 1, &hbuf[1][0], &hbuf[0][0], SB);
  }

  // FC + sigmoid (final h is in hbuf[0])
  if (w == 0) {
    const unsigned char* hbF = &hbuf[0][0];
    float part = 0.f;
    for (int i = 0; i < 25; ++i) {
      const int u = g * 25 + i;
      const unsigned off = ((unsigned)(row * 256 + u * 2)) ^ swz;
      const unsigned short vh = *reinterpret_cast<const unsigned short*>(hbF + off);
      const float hv = __uint_as_float((unsigned)vh << 16);
      part += hv * fcW[u];
    }
    red[l] = part;
  }
  __syncthreads();
  if (tid < RB) {
    const float s = red[tid] + red[tid + 16] + red[tid + 32] + red[tid + 48] + fcb[0];
    out[row0 + tid] = 1.0f / (1.0f + __expf(-s));
  }
}

// ---------------- fallback: exact fp32 wave kernel (needs P in ws) -------------
__global__ __launch_bounds__(64)
__attribute__((amdgpu_waves_per_eu(2, 2)))
void rnn_wave_kernel(
    const int* __restrict__ x, const float* __restrict__ P,
    const float* __restrict__ Whh,
    const float* __restrict__ fcW, const float* __restrict__ fcb,
    float* __restrict__ out)
{
  __shared__ float h_lds[2][112];
  const int row = blockIdx.x;
  const int l = threadIdx.x;
  const int u0 = l;
  const bool m1 = (l < HIDDEN - 64);
  const int u1 = m1 ? (64 + l) : (HIDDEN - 1);

  float w0[HIDDEN], w1[HIDDEN];
  #pragma unroll
  for (int k = 0; k < HIDDEN; k += 4) {
    const float4 a = *reinterpret_cast<const float4*>(&Whh[u0 * HIDDEN + k]);
    w0[k] = a.x; w0[k+1] = a.y; w0[k+2] = a.z; w0[k+3] = a.w;
    const float4 b = *reinterpret_cast<const float4*>(&Whh[u1 * HIDDEN + k]);
    w1[k] = b.x; w1[k+1] = b.y; w1[k+2] = b.z; w1[k+3] = b.w;
  }
  const float fw0 = fcW[u0];
  const float fw1 = m1 ? fcW[u1] : 0.f;

  h_lds[0][l] = 0.f;
  h_lds[0][l + 48] = 0.f;

  const int* __restrict__ xrow = x + (size_t)row * TSTEPS;
  const int i0 = xrow[0];
  float xp0 = P[i0 * HIDDEN + u0];
  float xp1 = P[i0 * HIDDEN + u1];
  int i_nx = xrow[1];

  float h0 = 0.f, h1 = 0.f;
  for (int t = 0; t < TSTEPS; ++t) {
    const int cur = t & 1, nxt = cur ^ 1;
    const float* __restrict__ Prow = P + i_nx * HIDDEN;
    const float xp0n = Prow[u0];
    const float xp1n = Prow[u1];
    i_nx = (t + 2 < TSTEPS) ? xrow[t + 2] : 0;

    float a0 = xp0, b0 = 0.f, a1v = xp1, b1 = 0.f;
    const float4* __restrict__ hb = reinterpret_cast<const float4*>(&h_lds[cur][0]);
    #pragma unroll
    for (int gq = 0; gq < HIDDEN / 4; ++gq) {
      const float4 hv = hb[gq];
      const int k = 4 * gq;
      if ((gq & 1) == 0) {
        a0  += w0[k]*hv.x + w0[k+1]*hv.y + w0[k+2]*hv.z + w0[k+3]*hv.w;
        a1v += w1[k]*hv.x + w1[k+1]*hv.y + w1[k+2]*hv.z + w1[k+3]*hv.w;
      } else {
        b0 += w0[k]*hv.x + w0[k+1]*hv.y + w0[k+2]*hv.z + w0[k+3]*hv.w;
        b1 += w1[k]*hv.x + w1[k+1]*hv.y + w1[k+2]*hv.z + w1[k+3]*hv.w;
      }
    }
    h0 = fast_tanh(a0 + b0);
    h1 = fast_tanh(a1v + b1);
    h_lds[nxt][u0] = h0;
    if (m1) h_lds[nxt][u1] = h1;
    xp0 = xp0n; xp1 = xp1n;
  }

  float s = h0 * fw0 + (m1 ? h1 * fw1 : 0.f);
  #pragma unroll
  for (int off = 32; off > 0; off >>= 1) s += __shfl_down(s, off);
  if (l == 0) out[row] = 1.0f / (1.0f + __expf(-(s + fcb[0])));
}

// ---------------- host ----------------------------------------------------------
extern "C" void kernel_launch(void* const* d_in, const int* in_sizes, int n_in,
                              void* d_out, int out_size, void* d_ws, size_t ws_size,
                              hipStream_t stream) {
  const int*   x     = (const int*)  d_in[0];
  const float* table = (const float*)d_in[1];
  const float* Wih   = (const float*)d_in[2];
  const float* Whh   = (const float*)d_in[3];
  const float* bih   = (const float*)d_in[4];
  const float* bhh   = (const float*)d_in[5];
  const float* fcW   = (const float*)d_in[6];
  const float* fcb   = (const float*)d_in[7];
  float* out = (float*)d_out;

  float* Pt = (float*)d_ws;

  if (ws_size >= WS_NEED) {
    proj_kernel<<<(VOCAB + 31) / 32, 256, 0, stream>>>(table, Wih, bih, bhh, Pt);
    rnn_mfma_kernel<<<NBLK, 512, 0, stream>>>(x, Pt, Whh, fcW, fcb, out);
  } else {
    proj_kernel<<<(VOCAB + 31) / 32, 256, 0, stream>>>(table, Wih, bih, bhh, Pt);
    rnn_wave_kernel<<<BATCH, 64, 0, stream>>>(x, Pt, Whh, fcW, fcb, out);
  }
}